// Round 6
// baseline (395.828 us; speedup 1.0000x reference)
//
#include <hip/hip_runtime.h>
#include <hip/hip_bf16.h>
#include <stdint.h>
#include <stddef.h>

// SimpleStateSpaceModel: B=4, S=4096, D=1024. FP32 in/out; bf16 MFMA inside.
// Pipeline (106 MB of d_ws — proven available in R4):
//   C0 cast_all         : x->xb (32MB), {dt_w,B_w,C_w}->wcat (6MB)
//   K1 gemm_async<bf16> : P[m,0:1024]=x@dt_w^T, P[m,1024:2048]=x@B_w^T
//   S1 scan_local       : g,u from (P,xb); in-place P <- [hl(t) | pg(t)];
//                         chunk totals -> Pc (gate product), Hl (local tail)
//   S3 scan_fix         : per-block inline carry prefix (L2-resident Pc/Hl),
//                         then h(t) = hl(t) + carry*pg(t) in place
//   K6 gemm_async<f32>  : out = h@C_w^T + D*x (xb epilogue)

#define Bdim 4
#define Sdim 4096
#define Dd   1024
#define Mdim (Bdim * Sdim)      // 16384
#define CCH  128                // scan chunks per sequence
#define LCH  (Sdim / CCH)       // 32 steps per chunk

typedef __attribute__((ext_vector_type(8))) short  short8;
typedef __attribute__((ext_vector_type(2))) short  short2v;
typedef __attribute__((ext_vector_type(4))) float  floatx4;
typedef __attribute__((ext_vector_type(2))) float  floatx2;

__device__ __forceinline__ float b2f(short v) {
  unsigned u = ((unsigned)(unsigned short)v) << 16;
  float f; __builtin_memcpy(&f, &u, 4); return f;
}
__device__ __forceinline__ short f2b(float f) {
  unsigned u; __builtin_memcpy(&u, &f, 4);
  u += 0x7fffu + ((u >> 16) & 1u);   // round-to-nearest-even
  return (short)(u >> 16);
}

__device__ __forceinline__ short8 ld8f(const float* p) {
  floatx4 lo = *(const floatx4*)p;
  floatx4 hi = *(const floatx4*)(p + 4);
  short8 r;
  r[0] = f2b(lo[0]); r[1] = f2b(lo[1]); r[2] = f2b(lo[2]); r[3] = f2b(lo[3]);
  r[4] = f2b(hi[0]); r[5] = f2b(hi[1]); r[6] = f2b(hi[2]); r[7] = f2b(hi[3]);
  return r;
}

__device__ __forceinline__ void st_out(short* p, float v) { *p = f2b(v); }
__device__ __forceinline__ void st_out(float* p, float v) { *p = v; }

// async 16B global->LDS (DMA). lds dest wave-uniform; lane i -> l + i*16. [m97]
__device__ __forceinline__ void cp16(const void* g, void* l) {
  __builtin_amdgcn_global_load_lds(
      (__attribute__((address_space(1))) void*)g,
      (__attribute__((address_space(3))) void*)l, 16, 0, 0);
}

// ---------------------------------------------------------------------------
// GEMM: Out[m,n] = sum_k A[m,k]*W[n,k], A/W bf16, async global->LDS staging.
// 128x128 tile, BK=32, 4 waves, 4x4 of 16x16x32 MFMA per wave. [R4/R5-verified]
// FUSE epilogue: Out += Dp[n] * b2f(Xr[m*ldx + n])   (Xr bf16)
// ---------------------------------------------------------------------------
template <typename OT, bool FUSE>
__global__ __launch_bounds__(256) void gemm_async(
    const short* __restrict__ A, int lda,
    const short* __restrict__ W,           // bf16 [N][K] row-major
    OT* __restrict__ Out, int ldo, int K,
    const float* __restrict__ Dp, const short* __restrict__ Xr, int ldx)
{
  __shared__ short As[128 * 32];
  __shared__ short Ws[128 * 32];

  const int tid = threadIdx.x;
  const int m0 = blockIdx.x * 128;
  const int n0 = blockIdx.y * 128;
  const short* Ap = A + (size_t)m0 * lda;
  const short* Wp = W + (size_t)n0 * K;

  const int lane = tid & 63;
  const int wv   = tid >> 6;
  const int wm   = (wv & 1) * 64;
  const int wn   = (wv >> 1) * 64;
  const int quad = lane >> 4;
  const int l16  = lane & 15;

  floatx4 acc[4][4] = {};

  // chunk c (16B = 8 bf16) at LDS offset c*16; covers row c>>2, cols (c&3)*8..
  const int cb  = wv * 128;
  const int cA0 = cb + lane, cA1 = cb + 64 + lane;
  const size_t gA0 = (size_t)(cA0 >> 2) * lda + (size_t)(cA0 & 3) * 8;
  const size_t gA1 = (size_t)(cA1 >> 2) * lda + (size_t)(cA1 & 3) * 8;
  const size_t gW0 = (size_t)(cA0 >> 2) * K   + (size_t)(cA0 & 3) * 8;
  const size_t gW1 = (size_t)(cA1 >> 2) * K   + (size_t)(cA1 & 3) * 8;

  for (int k0 = 0; k0 < K; k0 += 32) {
    __syncthreads();
    cp16(Ap + gA0 + k0, As + (size_t)cb * 8);
    cp16(Ap + gA1 + k0, As + (size_t)(cb + 64) * 8);
    cp16(Wp + gW0 + k0, Ws + (size_t)cb * 8);
    cp16(Wp + gW1 + k0, Ws + (size_t)(cb + 64) * 8);
    __syncthreads();

    short8 af[4], wf[4];
#pragma unroll
    for (int i = 0; i < 4; i++)   // A-frag: A[m = l16][k = quad*8 + j]
      af[i] = *(const short8*)(As + (wm + i * 16 + l16) * 32 + quad * 8);
#pragma unroll
    for (int i = 0; i < 4; i++)   // B-frag: W[n = l16][k = quad*8 + j]
      wf[i] = *(const short8*)(Ws + (wn + i * 16 + l16) * 32 + quad * 8);
#pragma unroll
    for (int mt = 0; mt < 4; mt++)
#pragma unroll
      for (int nt = 0; nt < 4; nt++)
        acc[mt][nt] = __builtin_amdgcn_mfma_f32_16x16x32_bf16(
            af[mt], wf[nt], acc[mt][nt], 0, 0, 0);
  }

  // C/D layout: row = quad*4 + r, col = l16  [verified m89/m91]
#pragma unroll
  for (int mt = 0; mt < 4; mt++) {
#pragma unroll
    for (int nt = 0; nt < 4; nt++) {
#pragma unroll
      for (int r = 0; r < 4; r++) {
        int m = m0 + wm + mt * 16 + quad * 4 + r;
        int n = n0 + wn + nt * 16 + l16;
        float v = acc[mt][nt][r];
        if (FUSE) v += Dp[n] * b2f(Xr[(size_t)m * ldx + n]);
        st_out(Out + (size_t)m * ldo + n, v);
      }
    }
  }
}

// ---------------------------------------------------------------------------
// C0: fused cast fp32->bf16 for x (16M elems) and the 3 weights (1M each).
// ---------------------------------------------------------------------------
__global__ __launch_bounds__(256) void cast_all(
    const float* __restrict__ x, const float* __restrict__ dt_w,
    const float* __restrict__ B_w, const float* __restrict__ C_w,
    short* __restrict__ xb, short* __restrict__ wcat)
{
  size_t i = ((size_t)blockIdx.x * 256 + threadIdx.x) * 8;
  const size_t NX = (size_t)Mdim * Dd;           // 16,777,216
  const size_t NW = (size_t)Dd * Dd;             // 1,048,576
  if (i < NX) {
    *(short8*)(xb + i) = ld8f(x + i);
  } else {
    size_t j = i - NX;
    const float* src = (j < NW) ? (dt_w + j)
                     : (j < 2 * NW) ? (B_w + (j - NW))
                                    : (C_w + (j - 2 * NW));
    *(short8*)(wcat + j) = ld8f(src);
  }
}

// ---------------------------------------------------------------------------
// Gate/input: z = dt_pre + dt_b; sp = softplus(z); g = exp(sp*-exp(A_log));
// u = sp * Bp * x.
// ---------------------------------------------------------------------------
__device__ __forceinline__ void gate_in(float dtp, float db, float nA,
                                        float bp, float xv,
                                        float& g, float& u) {
  float z  = dtp + db;
  float sp = fmaxf(z, 0.f) + log1pf(expf(-fabsf(z)));
  g = expf(sp * nA);
  u = sp * bp * xv;
}

// ---------------------------------------------------------------------------
// S1: single transcendental pass. Block = (b,c) chunk, 512 threads, 2 d each
// (16 waves/CU at 2 blocks/CU). In-place over P:
//   dt_pre slot <- hl(t) (running local scan, bf16)
//   Bp slot     <- pg(t) (running gate prefix-product, bf16)
// fp32 running values in registers; stores single-rounded.
// Chunk totals: Pc = prod(g), Hl = local tail.
// ---------------------------------------------------------------------------
__global__ __launch_bounds__(512) void scan_local(
    short* __restrict__ P, const short* __restrict__ xb,
    const float* __restrict__ dt_b, const float* __restrict__ A_log,
    const float* __restrict__ h0,
    float* __restrict__ Pc, float* __restrict__ Hl)
{
  const int b  = blockIdx.x >> 7;
  const int c  = blockIdx.x & 127;
  const int d0 = threadIdx.x * 2;

  floatx2 db = *(const floatx2*)(dt_b + d0);
  floatx2 al = *(const floatx2*)(A_log + d0);
  float nA[2] = {-expf(al[0]), -expf(al[1])};
  float p[2] = {1.f, 1.f}, h[2] = {0.f, 0.f};

  const size_t mrow = (size_t)b * Sdim + (size_t)c * LCH;
  for (int t = 0; t < LCH; t++) {
    size_t m = mrow + t;
    short2v dt2 = *(const short2v*)(P + m * 2048 + d0);
    short2v bp2 = *(const short2v*)(P + m * 2048 + 1024 + d0);
    short2v xv2 = *(const short2v*)(xb + m * Dd + d0);
    short2v hl2, pg2;
#pragma unroll
    for (int j = 0; j < 2; j++) {
      float g, u;
      gate_in(b2f(dt2[j]), db[j], nA[j], b2f(bp2[j]), b2f(xv2[j]), g, u);
      if (c == 0 && t == 0) u += g * h0[b * Dd + d0 + j];
      h[j] = g * h[j] + u;
      p[j] *= g;
      hl2[j] = f2b(h[j]);
      pg2[j] = f2b(p[j]);
    }
    *(short2v*)(P + m * 2048 + d0)        = hl2;   // own addrs: safe in-place
    *(short2v*)(P + m * 2048 + 1024 + d0) = pg2;
  }
  size_t o = ((size_t)b * CCH + c) * Dd + d0;
  *(floatx2*)(Pc + o) = floatx2{p[0], p[1]};
  *(floatx2*)(Hl + o) = floatx2{h[0], h[1]};
}

// ---------------------------------------------------------------------------
// S3: inline carry + chain-free fixup. Block = (b,c), 512 threads, 2 d each.
// Carry-in recomputed per block from Pc/Hl (L2-resident 4 MB; loads pipeline,
// only the fma chains — ~c iters). Then h(t) = hl(t) + carry*pg(t), in place.
// ---------------------------------------------------------------------------
__global__ __launch_bounds__(512) void scan_fix(
    short* __restrict__ P,
    const float* __restrict__ Pc, const float* __restrict__ Hl)
{
  const int b  = blockIdx.x >> 7;
  const int c  = blockIdx.x & 127;
  const int d0 = threadIdx.x * 2;

  float st0 = 0.f, st1 = 0.f;
  const size_t cbase = (size_t)b * CCH * Dd + d0;
#pragma unroll 4
  for (int cc = 0; cc < c; cc++) {
    floatx2 pv = *(const floatx2*)(Pc + cbase + (size_t)cc * Dd);
    floatx2 hv = *(const floatx2*)(Hl + cbase + (size_t)cc * Dd);
    st0 = pv[0] * st0 + hv[0];
    st1 = pv[1] * st1 + hv[1];
  }

  const size_t mrow = (size_t)b * Sdim + (size_t)c * LCH;
  for (int t = 0; t < LCH; t++) {
    size_t m = mrow + t;
    short2v hl2 = *(const short2v*)(P + m * 2048 + d0);
    short2v pg2 = *(const short2v*)(P + m * 2048 + 1024 + d0);
    short2v o2;
    o2[0] = f2b(b2f(hl2[0]) + st0 * b2f(pg2[0]));
    o2[1] = f2b(b2f(hl2[1]) + st1 * b2f(pg2[1]));
    *(short2v*)(P + m * 2048 + d0) = o2;           // h over hl slot
  }
}

// ---------------------------------------------------------------------------
extern "C" void kernel_launch(void* const* d_in, const int* in_sizes, int n_in,
                              void* d_out, int out_size, void* d_ws, size_t ws_size,
                              hipStream_t stream)
{
  const float* x     = (const float*)d_in[0];  // [4,4096,1024] fp32
  const float* h0    = (const float*)d_in[1];  // [4,1024]
  const float* dt_w  = (const float*)d_in[2];  // [1024,1024]
  const float* dt_b  = (const float*)d_in[3];  // [1024]
  const float* A_log = (const float*)d_in[4];  // [1024]
  const float* B_w   = (const float*)d_in[5];  // [1024,1024]
  const float* C_w   = (const float*)d_in[6];  // [1024,1024]
  const float* Dp    = (const float*)d_in[7];  // [1024]
  float* out = (float*)d_out;                  // [4,4096,1024] fp32

  // ws layout (106 MB):
  //   [0,64)    P bf16 [16384][2048]: dt_pre|Bp -> hl|pg -> h|pg
  //   [64,96)   xb bf16 [16384][1024]
  //   [96,102)  wcat bf16 [3072][1024]  (dt_w | B_w | C_w)
  //   [102,104) Pc fp32 [4][128][1024]  (chunk gate products)
  //   [104,106) Hl fp32 [4][128][1024]  (chunk local tails)
  char* ws = (char*)d_ws;
  short* P    = (short*)(ws);
  short* xb   = (short*)(ws + (64ull  << 20));
  short* wcat = (short*)(ws + (96ull  << 20));
  float* Pc   = (float*)(ws + (102ull << 20));
  float* Hl   = (float*)(ws + (104ull << 20));

  // C0: all casts in one launch: (16M + 3M)/8/256 = 9728 blocks
  cast_all<<<9728, 256, 0, stream>>>(x, dt_w, B_w, C_w, xb, wcat);

  // K1: P = x @ [dt_w;B_w]^T  (M=16384, N=2048, K=1024)
  gemm_async<short, false><<<dim3(Mdim / 128, 16), 256, 0, stream>>>(
      xb, Dd, wcat, P, 2048, 1024, nullptr, nullptr, 0);

  // S1 + S3: chunked scan (transcendentals once; carry inline in S3)
  scan_local<<<Bdim * CCH, 512, 0, stream>>>(P, xb, dt_b, A_log, h0, Pc, Hl);
  scan_fix<<<Bdim * CCH, 512, 0, stream>>>(P, Pc, Hl);

  // K6: out = h @ C_w^T + D*x  (h bf16 in P lda=2048; D*x epilogue from xb)
  gemm_async<float, true><<<dim3(Mdim / 128, 8), 256, 0, stream>>>(
      P, 2048, wcat + 2 * 1024 * 1024, out, Dd, 1024, Dp, xb, Dd);
}